// Round 6
// baseline (167.858 us; speedup 1.0000x reference)
//
#include <hip/hip_runtime.h>
#include <cstdint>

// CapsuleLayer dynamic routing: B=256, R=1152, C=10, O=16, I=8, 3 iters.
// Inputs fp32 (verified: bf16 reads NaN'd, fp32 reads gave finite identical
// results across two kernels). Output fp32 (reference output dtype).
// Decomposition: independent over (b,c) — softmax over r per (b,c), squash
// over o per (b,c), logit uses only capsule c's own v. One block per (b,c);
// u[r,o] cached in LDS (bf16) across the three passes. b_ij never stored:
// with b0=0, logit_k = u . (v0 + ... + v_{k-1}).
#define BB 256
#define RR 1152
#define CC 10
#define OO 16
#define II 8

__device__ __forceinline__ uint32_t f2bf(float f) {
    union U { float f; uint32_t i; } v; v.f = f;
    return (v.i + 0x7fffu + ((v.i >> 16) & 1u)) >> 16;   // RNE
}
__device__ __forceinline__ float bf2f(uint16_t h) {
    union U { uint32_t i; float f; } v; v.i = ((uint32_t)h) << 16;
    return v.f;
}

__global__ __launch_bounds__(256)
void k_caps(const float* __restrict__ x, const float* __restrict__ W,
            float* __restrict__ out) {
    __shared__ uint16_t u_lds[RR * 17];   // 39,168 B; stride 17 halfwords
    __shared__ float part[4][17];
    __shared__ float sarr[OO];
    __shared__ float wsumv[OO];

    const int t = threadIdx.x;
    const int c = blockIdx.x >> 8;    // c-major: 256 consecutive blocks share
    const int b = blockIdx.x & 255;   // the same 3.7 MB W-slice (L2-hot)
    const int rg = t >> 4, o = t & 15;

    // ---- Phase 1: u[r,o] = sum_i W[r,c,o,i] * x[b,r,i]  -> LDS (bf16) ----
    for (int it = 0; it < RR / 16; ++it) {
        const int r = it * 16 + rg;
        const float* wp = W + (((size_t)r * CC + c) * OO + o) * II;
        const float* xp = x + ((size_t)b * RR + r) * II;
        float4 w0 = *reinterpret_cast<const float4*>(wp);
        float4 w1 = *reinterpret_cast<const float4*>(wp + 4);
        float4 x0 = *reinterpret_cast<const float4*>(xp);
        float4 x1 = *reinterpret_cast<const float4*>(xp + 4);
        float u = 0.0f;
        u = fmaf(w0.x, x0.x, u); u = fmaf(w0.y, x0.y, u);
        u = fmaf(w0.z, x0.z, u); u = fmaf(w0.w, x0.w, u);
        u = fmaf(w1.x, x1.x, u); u = fmaf(w1.y, x1.y, u);
        u = fmaf(w1.z, x1.z, u); u = fmaf(w1.w, x1.w, u);
        u_lds[r * 17 + o] = (uint16_t)f2bf(u);
    }
    __syncthreads();

    // ---- Phase 2: three routing passes entirely from LDS ----
    for (int pass = 0; pass < 3; ++pass) {
        float wreg[OO];
        if (pass) {
#pragma unroll
            for (int k = 0; k < OO; ++k) wreg[k] = wsumv[k];  // broadcast
        }
        float num[OO];
#pragma unroll
        for (int k = 0; k < OO; ++k) num[k] = 0.0f;
        float den = 0.0f;

        for (int r = t; r < RR; r += 256) {
            float ur[OO];
#pragma unroll
            for (int k = 0; k < OO; ++k) ur[k] = bf2f(u_lds[r * 17 + k]);
            if (pass == 0) {
#pragma unroll
                for (int k = 0; k < OO; ++k) num[k] += ur[k];
            } else {
                float lg = 0.0f;
#pragma unroll
                for (int k = 0; k < OO; ++k) lg = fmaf(ur[k], wreg[k], lg);
                float e = __expf(lg);   // |logit| <~ 50: fp32-safe, no max-sub
                den += e;
#pragma unroll
                for (int k = 0; k < OO; ++k) num[k] = fmaf(e, ur[k], num[k]);
            }
        }

        // wave butterfly, then cross-wave combine via tiny LDS
#pragma unroll
        for (int m = 1; m < 64; m <<= 1) {
#pragma unroll
            for (int k = 0; k < OO; ++k) num[k] += __shfl_xor(num[k], m);
            den += __shfl_xor(den, m);
        }
        const int wv = t >> 6;
        if ((t & 63) == 0) {
#pragma unroll
            for (int k = 0; k < OO; ++k) part[wv][k] = num[k];
            part[wv][16] = den;
        }
        __syncthreads();

        float s = 0.0f;
        if (t < OO) {
            float nf = 0.0f, df = 0.0f;
#pragma unroll
            for (int j = 0; j < 4; ++j) { nf += part[j][t]; df += part[j][16]; }
            if (pass == 0) df = (float)RR;   // softmax(0) = 1/R
            s = nf / df;
            sarr[t] = s;
        }
        __syncthreads();
        if (t < OO) {
            float ss = 0.0f;
#pragma unroll
            for (int j = 0; j < OO; ++j) ss += sarr[j] * sarr[j];
            float v = s * (ss / ((1.0f + ss) * sqrtf(ss + 1e-7f)));
            if (pass == 2)
                out[(size_t)b * (CC * OO) + c * OO + t] = v;   // fp32 out
            else
                wsumv[t] = (pass == 0) ? v : (wsumv[t] + v);
        }
        __syncthreads();
    }
}

extern "C" void kernel_launch(void* const* d_in, const int* in_sizes, int n_in,
                              void* d_out, int out_size, void* d_ws, size_t ws_size,
                              hipStream_t stream) {
    const float* x = (const float*)d_in[0];  // (B,R,I) fp32
    const float* W = (const float*)d_in[1];  // (R,C,O,I) fp32
    // defensive: element counts are dtype-independent; swap if order differs
    if (n_in >= 2 && in_sizes[0] == RR * CC * OO * II &&
        in_sizes[1] == BB * RR * II) {
        const float* tmp = x; x = W; W = tmp;
    }
    float* out = (float*)d_out;              // (B,1,C,O,1) fp32

    k_caps<<<BB * CC, 256, 0, stream>>>(x, W, out);
}